// Round 4
// baseline (341.648 us; speedup 1.0000x reference)
//
#include <hip/hip_runtime.h>
#include <hip/hip_bf16.h>

#define B_ 8
#define N_ 2048
#define D_ 128

typedef __attribute__((ext_vector_type(8))) _Float16 half8;
typedef __attribute__((ext_vector_type(4))) float floatx4;

__device__ __forceinline__ unsigned short f2h(float f) {
    _Float16 h = (_Float16)f;                  // v_cvt_f16_f32, RNE
    union { _Float16 h; unsigned short u; } v; v.h = h;
    return v.u;
}

// ---------------------------------------------------------------------------
// proj: out[row][o] = sum_d x[row][d] * W[o][d]   (fp16 out, fp32 in)
// grid.x = 256 row-tiles of 64, grid.y = 4 : (x1,Wk)->h1 (x2,Wk)->h2 (x1,Wv)->v1 (x2,Wv)->v2
// ---------------------------------------------------------------------------
__global__ __launch_bounds__(256)
void proj_kernel(const float* __restrict__ x1, const float* __restrict__ x2,
                 const float* __restrict__ Wk, const float* __restrict__ Wv,
                 unsigned short* __restrict__ h1, unsigned short* __restrict__ h2,
                 unsigned short* __restrict__ v1, unsigned short* __restrict__ v2)
{
    __shared__ unsigned short Xs[64][136];
    __shared__ unsigned short Ws[128][136];
    const int which = blockIdx.y;
    const float* x = (which & 1) ? x2 : x1;
    const float* W = (which & 2) ? Wv : Wk;
    unsigned short* out = (which == 0) ? h1 : (which == 1) ? h2 : (which == 2) ? v1 : v2;
    const int rowbase = blockIdx.x * 64;
    const int t = threadIdx.x;

    for (int it = 0; it < 8; ++it) {                 // X tile 64x128 fp32->fp16
        int idx = t + 256 * it;
        int r = idx >> 5, c = (idx & 31) * 4;
        float4 f = *(const float4*)(x + (size_t)(rowbase + r) * 128 + c);
        Xs[r][c] = f2h(f.x); Xs[r][c+1] = f2h(f.y); Xs[r][c+2] = f2h(f.z); Xs[r][c+3] = f2h(f.w);
    }
    for (int it = 0; it < 16; ++it) {                // W 128x128 fp32->fp16
        int idx = t + 256 * it;
        int r = idx >> 5, c = (idx & 31) * 4;
        float4 f = *(const float4*)(W + (size_t)r * 128 + c);
        Ws[r][c] = f2h(f.x); Ws[r][c+1] = f2h(f.y); Ws[r][c+2] = f2h(f.z); Ws[r][c+3] = f2h(f.w);
    }
    __syncthreads();

    const int lane = t & 63, wave = t >> 6, l15 = lane & 15, quad = lane >> 4;
    half8 a[4];
    for (int ks = 0; ks < 4; ++ks)
        a[ks] = *(const half8*)&Xs[wave * 16 + l15][ks * 32 + quad * 8];

    for (int c = 0; c < 8; ++c) {
        floatx4 acc = {0.f, 0.f, 0.f, 0.f};
        for (int ks = 0; ks < 4; ++ks) {
            half8 b = *(const half8*)&Ws[c * 16 + l15][ks * 32 + quad * 8];
            acc = __builtin_amdgcn_mfma_f32_16x16x32_f16(a[ks], b, acc, 0, 0, 0);
        }
        int col = c * 16 + l15;
        for (int r = 0; r < 4; ++r) {
            int row = rowbase + wave * 16 + quad * 4 + r;
            out[(size_t)row * 128 + col] = f2h(acc[r]);
        }
    }
}

// ---------------------------------------------------------------------------
// rowstats: per row q of E[q,key] = Q[q]·K[key]:  m = max_key E,  l = sum exp(E-m)
// online (flash-style), one pass, no atomics. grid = (32 q-tiles, 8 batches)
// ---------------------------------------------------------------------------
__global__ __launch_bounds__(256)
void rowstats_kernel(const unsigned short* __restrict__ Qg, const unsigned short* __restrict__ Kg,
                     float* __restrict__ msum, float* __restrict__ lsum)
{
    __shared__ unsigned short Qs[64][136];
    __shared__ unsigned short Ks[64][136];
    const int b = blockIdx.y, qbase = blockIdx.x * 64, t = threadIdx.x;
    const unsigned short* Q = Qg + (size_t)b * N_ * 128;
    const unsigned short* K = Kg + (size_t)b * N_ * 128;

    for (int it = 0; it < 4; ++it) {
        int idx = t + 256 * it;
        int r = idx >> 4, c = (idx & 15) * 8;
        *(half8*)&Qs[r][c] = *(const half8*)(Q + (size_t)(qbase + r) * 128 + c);
    }
    __syncthreads();
    const int lane = t & 63, wave = t >> 6, l15 = lane & 15, quad = lane >> 4;
    half8 a[4];
    for (int ks = 0; ks < 4; ++ks)
        a[ks] = *(const half8*)&Qs[wave * 16 + l15][ks * 32 + quad * 8];

    float m[4] = {-1e30f, -1e30f, -1e30f, -1e30f};
    float l[4] = {0.f, 0.f, 0.f, 0.f};

    for (int kt = 0; kt < 32; ++kt) {
        __syncthreads();
        for (int it = 0; it < 4; ++it) {
            int idx = t + 256 * it;
            int r = idx >> 4, c = (idx & 15) * 8;
            *(half8*)&Ks[r][c] = *(const half8*)(K + (size_t)(kt * 64 + r) * 128 + c);
        }
        __syncthreads();
        floatx4 av[4];
        for (int c = 0; c < 4; ++c) {
            floatx4 acc = {0.f, 0.f, 0.f, 0.f};
            for (int ks = 0; ks < 4; ++ks) {
                half8 bb = *(const half8*)&Ks[c * 16 + l15][ks * 32 + quad * 8];
                acc = __builtin_amdgcn_mfma_f32_16x16x32_f16(a[ks], bb, acc, 0, 0, 0);
            }
            av[c] = acc;
        }
        for (int r = 0; r < 4; ++r) {
            float tm = fmaxf(fmaxf(av[0][r], av[1][r]), fmaxf(av[2][r], av[3][r]));
            float nm = fmaxf(m[r], tm);
            float s = __expf(av[0][r] - nm) + __expf(av[1][r] - nm)
                    + __expf(av[2][r] - nm) + __expf(av[3][r] - nm);
            l[r] = l[r] * __expf(m[r] - nm) + s;
            m[r] = nm;
        }
    }
    // merge (m,l) across the 16 l15-lanes of each quad
    for (int r = 0; r < 4; ++r) {
        float mm = m[r], ll = l[r];
        for (int off = 1; off <= 8; off <<= 1) {
            float om = __shfl_xor(mm, off, 64);
            float ol = __shfl_xor(ll, off, 64);
            float nm = fmaxf(mm, om);
            ll = ll * __expf(mm - nm) + ol * __expf(om - nm);
            mm = nm;
        }
        if (l15 == 0) {
            size_t row = (size_t)b * N_ + qbase + wave * 16 + quad * 4 + r;
            msum[row] = mm;
            lsum[row] = ll;
        }
    }
}

// ---------------------------------------------------------------------------
// attn: out[q][o] = leakyrelu( (sum_key exp(Q[q]·K[key] - smax[key]) / ssum[key] * V[key][:]) · Wo^T + bo )
// grid = (32 q-tiles, 8 batches), block 256
// ---------------------------------------------------------------------------
__global__ __launch_bounds__(256)
void attn_kernel(const unsigned short* __restrict__ Qg, const unsigned short* __restrict__ Kg,
                 const unsigned short* __restrict__ Vg,
                 const float* __restrict__ smaxg, const float* __restrict__ ssumg,
                 const float* __restrict__ Wo, const float* __restrict__ bo,
                 float* __restrict__ outp)
{
    __shared__ unsigned short Qs[64][136];
    __shared__ unsigned short Ks[64][136];
    __shared__ unsigned short Vt[128][72];   // transposed V tile: [d][key]
    __shared__ unsigned short Ps[64][72];    // P round-trip:      [q][key]
    const int b = blockIdx.y, qbase = blockIdx.x * 64, t = threadIdx.x;
    const unsigned short* Q = Qg + (size_t)b * N_ * 128;
    const unsigned short* K = Kg + (size_t)b * N_ * 128;
    const unsigned short* V = Vg + (size_t)b * N_ * 128;
    const float* SM = smaxg + (size_t)b * N_;
    const float* SL = ssumg + (size_t)b * N_;

    for (int it = 0; it < 4; ++it) {
        int idx = t + 256 * it;
        int r = idx >> 4, c = (idx & 15) * 8;
        *(half8*)&Qs[r][c] = *(const half8*)(Q + (size_t)(qbase + r) * 128 + c);
    }
    __syncthreads();
    const int lane = t & 63, wave = t >> 6, l15 = lane & 15, quad = lane >> 4;
    half8 a[4];
    for (int ks = 0; ks < 4; ++ks)
        a[ks] = *(const half8*)&Qs[wave * 16 + l15][ks * 32 + quad * 8];

    floatx4 oacc[8];
    for (int d = 0; d < 8; ++d) oacc[d] = (floatx4){0.f, 0.f, 0.f, 0.f};

    for (int kt = 0; kt < 32; ++kt) {
        __syncthreads();
        for (int it = 0; it < 4; ++it) {                   // K tile (row-major)
            int idx = t + 256 * it;
            int r = idx >> 4, c = (idx & 15) * 8;
            *(half8*)&Ks[r][c] = *(const half8*)(K + (size_t)(kt * 64 + r) * 128 + c);
        }
        for (int it = 0; it < 8; ++it) {                   // V tile transposed
            int idx = t + 256 * it;
            int key = idx & 63, d4 = idx >> 6;
            ushort4 vv = *(const ushort4*)(V + (size_t)(kt * 64 + key) * 128 + d4 * 4);
            Vt[d4 * 4 + 0][key] = vv.x; Vt[d4 * 4 + 1][key] = vv.y;
            Vt[d4 * 4 + 2][key] = vv.z; Vt[d4 * 4 + 3][key] = vv.w;
        }
        __syncthreads();
        // E tile + stabilized exp + per-key scale -> Ps (fp16, A-layout source)
        for (int c = 0; c < 4; ++c) {
            floatx4 acc = {0.f, 0.f, 0.f, 0.f};
            for (int ks = 0; ks < 4; ++ks) {
                half8 bb = *(const half8*)&Ks[c * 16 + l15][ks * 32 + quad * 8];
                acc = __builtin_amdgcn_mfma_f32_16x16x32_f16(a[ks], bb, acc, 0, 0, 0);
            }
            int key = kt * 64 + c * 16 + l15;
            float mx = SM[key];
            float inv = 1.0f / SL[key];                    // ssum >= 1 by construction
            for (int r = 0; r < 4; ++r) {
                float w = __expf(acc[r] - mx) * inv;       // exponent <= ~0: no overflow
                Ps[wave * 16 + quad * 4 + r][c * 16 + l15] = f2h(w);
            }
        }
        __syncthreads();
        // PV: O[q][d] += P[q][key] * V[key][d]
        half8 pa[2];
        for (int ks = 0; ks < 2; ++ks)
            pa[ks] = *(const half8*)&Ps[wave * 16 + l15][ks * 32 + quad * 8];
        for (int d = 0; d < 8; ++d) {
            for (int ks = 0; ks < 2; ++ks) {
                half8 vb = *(const half8*)&Vt[d * 16 + l15][ks * 32 + quad * 8];
                oacc[d] = __builtin_amdgcn_mfma_f32_16x16x32_f16(pa[ks], vb, oacc[d], 0, 0, 0);
            }
        }
    }
    __syncthreads();
    // n-tile (C-layout) -> fp16 into Ks[q][d] for the fused output projection
    for (int d = 0; d < 8; ++d) {
        int col = d * 16 + l15;
        for (int r = 0; r < 4; ++r)
            Ks[wave * 16 + quad * 4 + r][col] = f2h(oacc[d][r]);
    }
    float* outrow = outp + (size_t)b * N_ * 128;
    for (int half = 0; half < 2; ++half) {
        __syncthreads();
        for (int it = 0; it < 8; ++it) {                   // Wo rows [64*half, +64) -> Qs
            int idx = t + 256 * it;
            int r = idx >> 5, c = (idx & 31) * 4;
            float4 f = *(const float4*)(Wo + (size_t)(half * 64 + r) * 128 + c);
            Qs[r][c] = f2h(f.x); Qs[r][c+1] = f2h(f.y); Qs[r][c+2] = f2h(f.z); Qs[r][c+3] = f2h(f.w);
        }
        __syncthreads();
        half8 na[4];
        for (int ks = 0; ks < 4; ++ks)
            na[ks] = *(const half8*)&Ks[wave * 16 + l15][ks * 32 + quad * 8];
        for (int c = 0; c < 4; ++c) {
            floatx4 acc = {0.f, 0.f, 0.f, 0.f};
            for (int ks = 0; ks < 4; ++ks) {
                half8 wb = *(const half8*)&Qs[c * 16 + l15][ks * 32 + quad * 8];
                acc = __builtin_amdgcn_mfma_f32_16x16x32_f16(na[ks], wb, acc, 0, 0, 0);
            }
            int o = half * 64 + c * 16 + l15;
            float bias = bo[o];
            for (int r = 0; r < 4; ++r) {
                float mval = acc[r] + bias;
                mval = (mval >= 0.0f) ? mval : 0.01f * mval;
                outrow[(size_t)(qbase + wave * 16 + quad * 4 + r) * 128 + o] = mval;
            }
        }
    }
}

// ---------------------------------------------------------------------------
// ws layout (12.85 MB): h1, h2, v1 (fp16, 4.19 MB each), rmax,rsum,cmax,csum (f32, 64 KB each).
// v2 (fp16, 4.19 MB) lives in the msg2 half of d_out — dead space until attn-2,
// which runs last and overwrites it only after attn-1 consumed it.
// ---------------------------------------------------------------------------
extern "C" void kernel_launch(void* const* d_in, const int* in_sizes, int n_in,
                              void* d_out, int out_size, void* d_ws, size_t ws_size,
                              hipStream_t stream)
{
    const float* x1 = (const float*)d_in[0];
    const float* x2 = (const float*)d_in[1];
    const float* Wk = (const float*)d_in[2];
    const float* Wv = (const float*)d_in[3];
    const float* Wo = (const float*)d_in[4];
    const float* bo = (const float*)d_in[5];
    float* out = (float*)d_out;

    const size_t nrow = (size_t)B_ * N_;           // 16384
    unsigned short* h1 = (unsigned short*)d_ws;
    unsigned short* h2 = h1 + nrow * 128;
    unsigned short* v1 = h2 + nrow * 128;
    float* rmax = (float*)(v1 + nrow * 128);
    float* rsum = rmax + nrow;
    float* cmax = rsum + nrow;
    float* csum = cmax + nrow;
    unsigned short* v2 = (unsigned short*)(out + nrow * 128);  // msg2 half of d_out

    proj_kernel<<<dim3(256, 4), 256, 0, stream>>>(x1, x2, Wk, Wv, h1, h2, v1, v2);
    rowstats_kernel<<<dim3(32, 8), 256, 0, stream>>>(h1, h2, rmax, rsum);  // rows of E
    rowstats_kernel<<<dim3(32, 8), 256, 0, stream>>>(h2, h1, cmax, csum);  // rows of E^T = cols of E
    attn_kernel<<<dim3(32, 8), 256, 0, stream>>>(h1, h2, v2, cmax, csum, Wo, bo, out);
    attn_kernel<<<dim3(32, 8), 256, 0, stream>>>(h2, h1, v1, rmax, rsum, Wo, bo, out + nrow * 128);
}

// Round 5
// 237.022 us; speedup vs baseline: 1.4414x; 1.4414x over previous
//
#include <hip/hip_runtime.h>
#include <hip/hip_bf16.h>

#define B_ 8
#define N_ 2048
#define D_ 128

typedef __attribute__((ext_vector_type(8))) _Float16 half8;
typedef __attribute__((ext_vector_type(4))) float floatx4;

__device__ __forceinline__ unsigned short f2h(float f) {
    _Float16 h = (_Float16)f;                  // v_cvt_f16_f32, RNE
    union { _Float16 h; unsigned short u; } v; v.h = h;
    return v.u;
}

// ---------------------------------------------------------------------------
// proj: out[row][o] = sum_d x[row][d] * W[o][d]   (fp16 out, fp32 in)
// grid.x = 256 row-tiles of 64, grid.y = 4 : (x1,Wk)->h1 (x2,Wk)->h2 (x1,Wv)->v1 (x2,Wv)->v2
// ---------------------------------------------------------------------------
__global__ __launch_bounds__(256)
void proj_kernel(const float* __restrict__ x1, const float* __restrict__ x2,
                 const float* __restrict__ Wk, const float* __restrict__ Wv,
                 unsigned short* __restrict__ h1, unsigned short* __restrict__ h2,
                 unsigned short* __restrict__ v1, unsigned short* __restrict__ v2)
{
    __shared__ unsigned short Xs[64][136];
    __shared__ unsigned short Ws[128][136];
    const int which = blockIdx.y;
    const float* x = (which & 1) ? x2 : x1;
    const float* W = (which & 2) ? Wv : Wk;
    unsigned short* out = (which == 0) ? h1 : (which == 1) ? h2 : (which == 2) ? v1 : v2;
    const int rowbase = blockIdx.x * 64;
    const int t = threadIdx.x;

    for (int it = 0; it < 8; ++it) {                 // X tile 64x128 fp32->fp16
        int idx = t + 256 * it;
        int r = idx >> 5, c = (idx & 31) * 4;
        float4 f = *(const float4*)(x + (size_t)(rowbase + r) * 128 + c);
        Xs[r][c] = f2h(f.x); Xs[r][c+1] = f2h(f.y); Xs[r][c+2] = f2h(f.z); Xs[r][c+3] = f2h(f.w);
    }
    for (int it = 0; it < 16; ++it) {                // W 128x128 fp32->fp16
        int idx = t + 256 * it;
        int r = idx >> 5, c = (idx & 31) * 4;
        float4 f = *(const float4*)(W + (size_t)r * 128 + c);
        Ws[r][c] = f2h(f.x); Ws[r][c+1] = f2h(f.y); Ws[r][c+2] = f2h(f.z); Ws[r][c+3] = f2h(f.w);
    }
    __syncthreads();

    const int lane = t & 63, wave = t >> 6, l15 = lane & 15, quad = lane >> 4;
    half8 a[4];
    for (int ks = 0; ks < 4; ++ks)
        a[ks] = *(const half8*)&Xs[wave * 16 + l15][ks * 32 + quad * 8];

    for (int c = 0; c < 8; ++c) {
        floatx4 acc = {0.f, 0.f, 0.f, 0.f};
        for (int ks = 0; ks < 4; ++ks) {
            half8 b = *(const half8*)&Ws[c * 16 + l15][ks * 32 + quad * 8];
            acc = __builtin_amdgcn_mfma_f32_16x16x32_f16(a[ks], b, acc, 0, 0, 0);
        }
        int col = c * 16 + l15;
        for (int r = 0; r < 4; ++r) {
            int row = rowbase + wave * 16 + quad * 4 + r;
            out[(size_t)row * 128 + col] = f2h(acc[r]);
        }
    }
}

// ---------------------------------------------------------------------------
// rowstats (both directions in one launch, blockIdx.z = dir):
//   dir0: rows of E  (Q=h1,K=h2) -> rmax,rsum ; dir1: rows of E^T (Q=h2,K=h1) -> cmax,csum
// grid = (32 q-tiles, 8 batches, 2 dirs), block 256
// ---------------------------------------------------------------------------
__global__ __launch_bounds__(256)
void rowstats_kernel(const unsigned short* __restrict__ h1g, const unsigned short* __restrict__ h2g,
                     float* __restrict__ rmax, float* __restrict__ rsum,
                     float* __restrict__ cmax, float* __restrict__ csum)
{
    __shared__ unsigned short Qs[64][136];
    __shared__ unsigned short Ks[64][136];
    const int b = blockIdx.y, qbase = blockIdx.x * 64, t = threadIdx.x;
    const int dir = blockIdx.z;
    const unsigned short* Q = (dir ? h2g : h1g) + (size_t)b * N_ * 128;
    const unsigned short* K = (dir ? h1g : h2g) + (size_t)b * N_ * 128;
    float* msum = dir ? cmax : rmax;
    float* lsum = dir ? csum : rsum;

    for (int it = 0; it < 4; ++it) {
        int idx = t + 256 * it;
        int r = idx >> 4, c = (idx & 15) * 8;
        *(half8*)&Qs[r][c] = *(const half8*)(Q + (size_t)(qbase + r) * 128 + c);
    }
    __syncthreads();
    const int lane = t & 63, wave = t >> 6, l15 = lane & 15, quad = lane >> 4;
    half8 a[4];
    for (int ks = 0; ks < 4; ++ks)
        a[ks] = *(const half8*)&Qs[wave * 16 + l15][ks * 32 + quad * 8];

    float m[4] = {-1e30f, -1e30f, -1e30f, -1e30f};
    float l[4] = {0.f, 0.f, 0.f, 0.f};

    for (int kt = 0; kt < 32; ++kt) {
        __syncthreads();
        for (int it = 0; it < 4; ++it) {
            int idx = t + 256 * it;
            int r = idx >> 4, c = (idx & 15) * 8;
            *(half8*)&Ks[r][c] = *(const half8*)(K + (size_t)(kt * 64 + r) * 128 + c);
        }
        __syncthreads();
        floatx4 av[4];
        for (int c = 0; c < 4; ++c) {
            floatx4 acc = {0.f, 0.f, 0.f, 0.f};
            for (int ks = 0; ks < 4; ++ks) {
                half8 bb = *(const half8*)&Ks[c * 16 + l15][ks * 32 + quad * 8];
                acc = __builtin_amdgcn_mfma_f32_16x16x32_f16(a[ks], bb, acc, 0, 0, 0);
            }
            av[c] = acc;
        }
        for (int r = 0; r < 4; ++r) {
            float tm = fmaxf(fmaxf(av[0][r], av[1][r]), fmaxf(av[2][r], av[3][r]));
            float nm = fmaxf(m[r], tm);
            float s = __expf(av[0][r] - nm) + __expf(av[1][r] - nm)
                    + __expf(av[2][r] - nm) + __expf(av[3][r] - nm);
            l[r] = l[r] * __expf(m[r] - nm) + s;
            m[r] = nm;
        }
    }
    // merge (m,l) across the 16 l15-lanes of each quad
    for (int r = 0; r < 4; ++r) {
        float mm = m[r], ll = l[r];
        for (int off = 1; off <= 8; off <<= 1) {
            float om = __shfl_xor(mm, off, 64);
            float ol = __shfl_xor(ll, off, 64);
            float nm = fmaxf(mm, om);
            ll = ll * __expf(mm - nm) + ol * __expf(om - nm);
            mm = nm;
        }
        if (l15 == 0) {
            size_t row = (size_t)b * N_ + qbase + wave * 16 + quad * 4 + r;
            msum[row] = mm;
            lsum[row] = ll;
        }
    }
}

// ---------------------------------------------------------------------------
// attn (direction = blockIdx.z + zbase):
//   dir0: Q=h1,K=h2,V=v2, stats=cmax/csum -> msg1 (out)
//   dir1: Q=h2,K=h1,V=v1, stats=rmax/rsum -> msg2 (out + nrow*128)
// out[q][o] = leakyrelu( (sum_key exp(QK - smax[key]) / ssum[key] * V[key]) · Wo^T + bo )
// grid = (32 q-tiles, 8 batches, 1-or-2 dirs), block 256
// ---------------------------------------------------------------------------
__global__ __launch_bounds__(256)
void attn_kernel(const unsigned short* __restrict__ h1g, const unsigned short* __restrict__ h2g,
                 const unsigned short* __restrict__ v1g, const unsigned short* __restrict__ v2g,
                 const float* __restrict__ rmax, const float* __restrict__ rsum,
                 const float* __restrict__ cmax, const float* __restrict__ csum,
                 const float* __restrict__ Wo, const float* __restrict__ bo,
                 float* __restrict__ outp, int zbase)
{
    __shared__ unsigned short Qs[64][136];
    __shared__ unsigned short Ks[64][136];
    __shared__ unsigned short Vt[128][72];   // transposed V tile: [d][key]
    __shared__ unsigned short Ps[64][72];    // P round-trip:      [q][key]
    const int b = blockIdx.y, qbase = blockIdx.x * 64, t = threadIdx.x;
    const int dir = blockIdx.z + zbase;
    const unsigned short* Q = (dir ? h2g : h1g) + (size_t)b * N_ * 128;
    const unsigned short* K = (dir ? h1g : h2g) + (size_t)b * N_ * 128;
    const unsigned short* V = (dir ? v1g : v2g) + (size_t)b * N_ * 128;
    const float* SM = (dir ? rmax : cmax) + (size_t)b * N_;
    const float* SL = (dir ? rsum : csum) + (size_t)b * N_;
    float* outbase = outp + (dir ? (size_t)B_ * N_ * 128 : 0);

    for (int it = 0; it < 4; ++it) {
        int idx = t + 256 * it;
        int r = idx >> 4, c = (idx & 15) * 8;
        *(half8*)&Qs[r][c] = *(const half8*)(Q + (size_t)(qbase + r) * 128 + c);
    }
    __syncthreads();
    const int lane = t & 63, wave = t >> 6, l15 = lane & 15, quad = lane >> 4;
    half8 a[4];
    for (int ks = 0; ks < 4; ++ks)
        a[ks] = *(const half8*)&Qs[wave * 16 + l15][ks * 32 + quad * 8];

    floatx4 oacc[8];
    for (int d = 0; d < 8; ++d) oacc[d] = (floatx4){0.f, 0.f, 0.f, 0.f};

    for (int kt = 0; kt < 32; ++kt) {
        __syncthreads();
        for (int it = 0; it < 4; ++it) {                   // K tile (row-major)
            int idx = t + 256 * it;
            int r = idx >> 4, c = (idx & 15) * 8;
            *(half8*)&Ks[r][c] = *(const half8*)(K + (size_t)(kt * 64 + r) * 128 + c);
        }
        for (int it = 0; it < 8; ++it) {                   // V tile transposed
            int idx = t + 256 * it;
            int key = idx & 63, d4 = idx >> 6;
            ushort4 vv = *(const ushort4*)(V + (size_t)(kt * 64 + key) * 128 + d4 * 4);
            Vt[d4 * 4 + 0][key] = vv.x; Vt[d4 * 4 + 1][key] = vv.y;
            Vt[d4 * 4 + 2][key] = vv.z; Vt[d4 * 4 + 3][key] = vv.w;
        }
        __syncthreads();
        // E tile + stabilized exp + per-key scale -> Ps (fp16, A-layout source)
        for (int c = 0; c < 4; ++c) {
            floatx4 acc = {0.f, 0.f, 0.f, 0.f};
            for (int ks = 0; ks < 4; ++ks) {
                half8 bb = *(const half8*)&Ks[c * 16 + l15][ks * 32 + quad * 8];
                acc = __builtin_amdgcn_mfma_f32_16x16x32_f16(a[ks], bb, acc, 0, 0, 0);
            }
            int key = kt * 64 + c * 16 + l15;
            float mx = SM[key];
            float inv = 1.0f / SL[key];                    // ssum >= 1 by construction
            for (int r = 0; r < 4; ++r) {
                float w = __expf(acc[r] - mx) * inv;       // exponent <= ~0: no overflow
                Ps[wave * 16 + quad * 4 + r][c * 16 + l15] = f2h(w);
            }
        }
        __syncthreads();
        // PV: O[q][d] += P[q][key] * V[key][d]
        half8 pa[2];
        for (int ks = 0; ks < 2; ++ks)
            pa[ks] = *(const half8*)&Ps[wave * 16 + l15][ks * 32 + quad * 8];
        for (int d = 0; d < 8; ++d) {
            for (int ks = 0; ks < 2; ++ks) {
                half8 vb = *(const half8*)&Vt[d * 16 + l15][ks * 32 + quad * 8];
                oacc[d] = __builtin_amdgcn_mfma_f32_16x16x32_f16(pa[ks], vb, oacc[d], 0, 0, 0);
            }
        }
    }
    __syncthreads();
    // n-tile (C-layout) -> fp16 into Ks[q][d] for the fused output projection
    for (int d = 0; d < 8; ++d) {
        int col = d * 16 + l15;
        for (int r = 0; r < 4; ++r)
            Ks[wave * 16 + quad * 4 + r][col] = f2h(oacc[d][r]);
    }
    for (int half = 0; half < 2; ++half) {
        __syncthreads();
        for (int it = 0; it < 8; ++it) {                   // Wo rows [64*half, +64) -> Qs
            int idx = t + 256 * it;
            int r = idx >> 5, c = (idx & 31) * 4;
            float4 f = *(const float4*)(Wo + (size_t)(half * 64 + r) * 128 + c);
            Qs[r][c] = f2h(f.x); Qs[r][c+1] = f2h(f.y); Qs[r][c+2] = f2h(f.z); Qs[r][c+3] = f2h(f.w);
        }
        __syncthreads();
        half8 na[4];
        for (int ks = 0; ks < 4; ++ks)
            na[ks] = *(const half8*)&Ks[wave * 16 + l15][ks * 32 + quad * 8];
        for (int c = 0; c < 4; ++c) {
            floatx4 acc = {0.f, 0.f, 0.f, 0.f};
            for (int ks = 0; ks < 4; ++ks) {
                half8 wb = *(const half8*)&Qs[c * 16 + l15][ks * 32 + quad * 8];
                acc = __builtin_amdgcn_mfma_f32_16x16x32_f16(na[ks], wb, acc, 0, 0, 0);
            }
            int o = half * 64 + c * 16 + l15;
            float bias = bo[o];
            for (int r = 0; r < 4; ++r) {
                float mval = acc[r] + bias;
                mval = (mval >= 0.0f) ? mval : 0.01f * mval;
                outbase[(size_t)(b * N_ + qbase + wave * 16 + quad * 4 + r) * 128 + o] = mval;
            }
        }
    }
}

// ---------------------------------------------------------------------------
// ws layout A (17.04 MB, if ws_size permits): h1,h2,v1,v2 fp16 + 4 stat arrays.
//   -> attn launched once with grid.z=2 (512 blocks, 2 blocks/CU).
// ws layout B (12.85 MB fallback): v2 lives in the msg2 half of d_out; attn
//   must then run as two sequential launches (dir1 overwrites v2's home).
// rowstats is always merged (grid.z=2): it only reads h1/h2, writes stats.
// ---------------------------------------------------------------------------
extern "C" void kernel_launch(void* const* d_in, const int* in_sizes, int n_in,
                              void* d_out, int out_size, void* d_ws, size_t ws_size,
                              hipStream_t stream)
{
    const float* x1 = (const float*)d_in[0];
    const float* x2 = (const float*)d_in[1];
    const float* Wk = (const float*)d_in[2];
    const float* Wv = (const float*)d_in[3];
    const float* Wo = (const float*)d_in[4];
    const float* bo = (const float*)d_in[5];
    float* out = (float*)d_out;

    const size_t nrow = (size_t)B_ * N_;           // 16384
    unsigned short* h1 = (unsigned short*)d_ws;
    unsigned short* h2 = h1 + nrow * 128;
    unsigned short* v1 = h2 + nrow * 128;
    const size_t need = 4 * nrow * 128 * sizeof(unsigned short) + 4 * nrow * sizeof(float);
    const bool fits = ws_size >= need;

    unsigned short* v2;
    float* rmax;
    if (fits) {
        v2 = v1 + nrow * 128;
        rmax = (float*)(v2 + nrow * 128);
    } else {
        v2 = (unsigned short*)(out + nrow * 128);  // msg2 half of d_out
        rmax = (float*)(v1 + nrow * 128);
    }
    float* rsum = rmax + nrow;
    float* cmax = rsum + nrow;
    float* csum = cmax + nrow;

    proj_kernel<<<dim3(256, 4), 256, 0, stream>>>(x1, x2, Wk, Wv, h1, h2, v1, v2);
    rowstats_kernel<<<dim3(32, 8, 2), 256, 0, stream>>>(h1, h2, rmax, rsum, cmax, csum);
    if (fits) {
        attn_kernel<<<dim3(32, 8, 2), 256, 0, stream>>>(h1, h2, v1, v2, rmax, rsum, cmax, csum,
                                                        Wo, bo, out, 0);
    } else {
        attn_kernel<<<dim3(32, 8, 1), 256, 0, stream>>>(h1, h2, v1, v2, rmax, rsum, cmax, csum,
                                                        Wo, bo, out, 0);
        attn_kernel<<<dim3(32, 8, 1), 256, 0, stream>>>(h1, h2, v1, v2, rmax, rsum, cmax, csum,
                                                        Wo, bo, out, 1);
    }
}